// Round 8
// baseline (36.750 us; speedup 1.0000x reference)
//
#include <hip/hip_runtime.h>
#include <math.h>

#define NN     1000
#define NPAD   1024
#define NTILE  32              /* n-tiles of 32 gaussians                  */
#define NSPLIT 4               /* waves per block (n-range split 4 x 256)  */
#define TPW    (NTILE/NSPLIT)  /* tiles per wave = 8                       */
#define DTHR   8.0f            /* defer-rescale threshold (log2 domain)    */
#define LOG2E  1.4426950408889634f
#define LN2PI  1.8378770664093453f

typedef float        f32x4 __attribute__((ext_vector_type(4)));
typedef _Float16     f16x8 __attribute__((ext_vector_type(8)));
typedef unsigned int u32x4v __attribute__((ext_vector_type(4)));

static __device__ __forceinline__ float bperm(int byteaddr, float v) {
    return __builtin_bit_cast(float,
        __builtin_amdgcn_ds_bpermute(byteaddr, __builtin_bit_cast(int, v)));
}

// ============ prep: per-gaussian params (SoA) + MFMA B-fragments ============
// ws layout:
//   kp[T][s][32]  f32, s in {0:p 1:q 2:u0 3:r 4:v0 5:K}   (24576 B)
//   bf[T][lane]   u32x4 = 8 f16 B-frag (col=lane&15: 0=alpha 1..3=rgb)  (32768 B)
// Cholesky log2-domain: k = K - u^2 - v^2; u = p*x + (q*y + u0); v = r*y + v0
__global__ __launch_bounds__(256) void splat_prep(
    const float* __restrict__ rho, const float* __restrict__ sigma,
    const float* __restrict__ coords, const float* __restrict__ alpha,
    const float* __restrict__ colors,
    float* __restrict__ kp, u32x4v* __restrict__ bf)
{
    int tid = blockIdx.x * 256 + threadIdx.x;
    if (tid < NPAD) {
        int n = tid;
        float p, q, r_, u0, v0, K;
        if (n >= NN) {              // dummy: can never win the max, adds 0
            p = q = r_ = u0 = v0 = 0.f; K = -1e30f;
        } else {
            float sx = tanhf(sigma[2*n]   * 0.5f) + 1e-4f;
            float sy = tanhf(sigma[2*n+1] * 0.5f) + 1e-4f;
            float rho_a = 1.0f / (1.0f + expf(-rho[n])) + 1e-6f;
            float cxx = sx*sx + 1e-6f;
            float cyy = sy*sy + 1e-6f;
            float cxy = sx*sy*rho_a;
            float det = cxx*cyy - cxy*cxy;
            float invdet = 1.0f / det;
            float hl = 0.5f * LOG2E;
            float a  = hl * cyy * invdet;
            float g  = -hl * cxy * invdet;
            p  = sqrtf(a);
            q  = g / p;
            r_ = sqrtf(hl / cyy);    // exact: b - q^2 = hl/cyy
            float cx = tanhf(coords[2*n])   - 0.5f;
            float cy = tanhf(coords[2*n+1]) - 0.5f;
            u0 = p*cx + q*cy;
            v0 = r_*cy;
            K  = (0.5f * logf(det + 1e-6f) - LN2PI) * LOG2E;
        }
        int T = n >> 5, nl = n & 31;
        float* b = kp + T*192 + nl;
        b[0]=p; b[32]=q; b[64]=u0; b[96]=r_; b[128]=v0; b[160]=K;
    } else if (tid < NPAD + 2048) {
        // B-fragment gather: lane l holds col=l&15, k-slots (l>>4)*8+j (j=2r+half)
        int t2 = tid - NPAD;
        int T = t2 >> 6, lane = t2 & 63, col = lane & 15, g = lane >> 4;
        unsigned w[4] = {0u, 0u, 0u, 0u};
        if (col < 4) {
            #pragma unroll
            for (int j = 0; j < 8; ++j) {
                int n = T*32 + g*8 + j;
                float act = 0.f;
                if (n < NN) {
                    float raw = (col == 0) ? alpha[n] : colors[3*n + col - 1];
                    act = 1.0f / (1.0f + expf(-raw));
                }
                _Float16 h = (_Float16)act;
                unsigned short u = __builtin_bit_cast(unsigned short, h);
                w[j >> 1] |= (unsigned)u << (16 * (j & 1));
            }
        }
        bf[T*64 + lane] = (u32x4v){w[0], w[1], w[2], w[3]};
    }
}

// ============ main: flash-splat, 32 px/block (one row), 4-way n-split ======
__global__ __launch_bounds__(256, 4) void splat_main(
    const float* __restrict__ kp, const u32x4v* __restrict__ bf,
    float* __restrict__ out)
{
    const int tid  = threadIdx.x;
    const int wave = tid >> 6, lane = tid & 63;
    const int pxbase = blockIdx.x * 32;          // 32 px, same image row
    const float step = 2.0f / 255.0f;
    const float y  = -1.0f + (float)(pxbase >> 8) * step;         // uniform
    const float x0 = -1.0f + (float)((pxbase & 255) + (lane & 15)) * step;
    const float x1 = x0 + 16.0f * step;
    const int g = lane >> 4;

    const int ab  = g << 4;                      // C-row bpermute base (bytes)
    const int a16 = ((lane ^ 16) & 63) << 2;     // butterfly addrs (bytes)
    const int a32 = ((lane ^ 32) & 63) << 2;

    f32x4 C0 = {0.f,0.f,0.f,0.f}, C1 = {0.f,0.f,0.f,0.f};
    float m0 = -INFINITY, m1 = -INFINITY;

    for (int t = 0; t < TPW; ++t) {
        const int T = wave * TPW + t;
        const f32x4* b4 = (const f32x4*)(kp + T*192 + g*8);
        // param loads: p,q,u0,r,v0,K — 12 x dwordx4
        f32x4 P0 = b4[0],  P1 = b4[1];
        f32x4 Q0 = b4[8],  Q1 = b4[9];
        f32x4 Ua = b4[16], Ub = b4[17];
        f32x4 R0 = b4[24], R1 = b4[25];
        f32x4 Va = b4[32], Vb = b4[33];
        f32x4 K0 = b4[40], K1 = b4[41];

        // block-uniform per-n terms: t_j = q*y + u0, K' = K - (r*y + v0)^2
        float pj[8], tj[8], Kp[8];
        #pragma unroll
        for (int j = 0; j < 4; ++j) {
            pj[j]   = P0[j];
            tj[j]   = fmaf(Q0[j], y, Ua[j]);
            float v = fmaf(R0[j], y, Va[j]);
            Kp[j]   = fmaf(-v, v, K0[j]);
            pj[j+4] = P1[j];
            tj[j+4] = fmaf(Q1[j], y, Ub[j]);
            float v2= fmaf(R1[j], y, Vb[j]);
            Kp[j+4] = fmaf(-v2, v2, K1[j]);
        }

        // k for 8 n x 2 px-tiles: 2 FMA each
        float k0[8], k1[8];
        #pragma unroll
        for (int j = 0; j < 8; ++j) {
            float u = fmaf(pj[j], x0, tj[j]); k0[j] = fmaf(-u, u, Kp[j]);
            float w = fmaf(pj[j], x1, tj[j]); k1[j] = fmaf(-w, w, Kp[j]);
        }
        float lm0 = fmaxf(fmaxf(fmaxf(k0[0],k0[1]),fmaxf(k0[2],k0[3])),
                          fmaxf(fmaxf(k0[4],k0[5]),fmaxf(k0[6],k0[7])));
        float lm1 = fmaxf(fmaxf(fmaxf(k1[0],k1[1]),fmaxf(k1[2],k1[3])),
                          fmaxf(fmaxf(k1[4],k1[5]),fmaxf(k1[6],k1[7])));

        // defer-rescale (T13): only when some row's max grew by > DTHR
        if (__any((lm0 > m0 + DTHR) | (lm1 > m1 + DTHR))) {
            float r0 = lm0, r1 = lm1;                  // butterfly -> row max
            r0 = fmaxf(r0, bperm(a16, r0)); r0 = fmaxf(r0, bperm(a32, r0));
            r1 = fmaxf(r1, bperm(a16, r1)); r1 = fmaxf(r1, bperm(a32, r1));
            float nm0 = fmaxf(m0, r0), nm1 = fmaxf(m1, r1);
            float s0 = __builtin_amdgcn_exp2f(m0 - nm0);
            float s1 = __builtin_amdgcn_exp2f(m1 - nm1);
            m0 = nm0; m1 = nm1;
            #pragma unroll
            for (int i = 0; i < 4; ++i) {              // scale C rows 4g+i
                C0[i] *= bperm(ab + 4*i, s0);
                C1[i] *= bperm(ab + 4*i, s1);
            }
        }

        // e = exp2(k - m), pack f16 pairs -> A fragments (j = 2r + half)
        unsigned w0[4], w1[4];
        #pragma unroll
        for (int r2 = 0; r2 < 4; ++r2) {
            float ea = __builtin_amdgcn_exp2f(k0[2*r2]   - m0);
            float eb = __builtin_amdgcn_exp2f(k0[2*r2+1] - m0);
            w0[r2] = __builtin_bit_cast(unsigned, __builtin_amdgcn_cvt_pkrtz(ea, eb));
            float ec = __builtin_amdgcn_exp2f(k1[2*r2]   - m1);
            float ed = __builtin_amdgcn_exp2f(k1[2*r2+1] - m1);
            w1[r2] = __builtin_bit_cast(unsigned, __builtin_amdgcn_cvt_pkrtz(ec, ed));
        }
        f16x8 A0 = __builtin_bit_cast(f16x8, (u32x4v){w0[0],w0[1],w0[2],w0[3]});
        f16x8 A1 = __builtin_bit_cast(f16x8, (u32x4v){w1[0],w1[1],w1[2],w1[3]});
        f16x8 Bf = __builtin_bit_cast(f16x8, bf[T*64 + lane]);

        C0 = __builtin_amdgcn_mfma_f32_16x16x32_f16(A0, Bf, C0, 0, 0, 0);
        C1 = __builtin_amdgcn_mfma_f32_16x16x32_f16(A1, Bf, C1, 0, 0, 0);
    }

    // ---- combine 4 per-wave partial softmax states (m, C) in LDS ----
    __shared__ float pm[NSPLIT][32];
    __shared__ float pc[NSPLIT][32][4];
    const int col = lane & 15;
    if (col < 4) {
        #pragma unroll
        for (int i = 0; i < 4; ++i) {     // C: col=lane&15, row=4*(lane>>4)+i
            pc[wave][     4*g + i][col] = C0[i];
            pc[wave][16 + 4*g + i][col] = C1[i];
        }
    }
    if (lane < 32) pm[wave][lane] = (lane < 16) ? m0 : m1;
    __syncthreads();

    if (tid < 32) {
        int px = tid;
        float M = pm[0][px];
        #pragma unroll
        for (int w = 1; w < NSPLIT; ++w) M = fmaxf(M, pm[w][px]);
        float A = 0.f, R = 0.f, G = 0.f, B = 0.f;
        #pragma unroll
        for (int w = 0; w < NSPLIT; ++w) {
            float s = __builtin_amdgcn_exp2f(pm[w][px] - M);
            A = fmaf(pc[w][px][0], s, A);
            R = fmaf(pc[w][px][1], s, R);
            G = fmaf(pc[w][px][2], s, G);
            B = fmaf(pc[w][px][3], s, B);
        }
        float inv = 1.0f / (A + 1e-6f);
        int q = (pxbase + px) * 3;
        out[q]   = R * inv;
        out[q+1] = G * inv;
        out[q+2] = B * inv;
    }
}

extern "C" void kernel_launch(void* const* d_in, const int* in_sizes, int n_in,
                              void* d_out, int out_size, void* d_ws, size_t ws_size,
                              hipStream_t stream) {
    const float* rho    = (const float*)d_in[0];
    const float* sigma  = (const float*)d_in[1];
    const float* coords = (const float*)d_in[2];
    const float* alpha  = (const float*)d_in[3];
    const float* colors = (const float*)d_in[4];
    const float* xy     = (const float*)d_in[5];  (void)xy; // coords derived analytically
    float* out = (float*)d_out;

    char* ws = (char*)d_ws;                   // 24576 + 32768 = 57344 B used
    float*  kp = (float*)ws;
    u32x4v* bf = (u32x4v*)(ws + 24576);

    splat_prep<<<12, 256, 0, stream>>>(rho, sigma, coords, alpha, colors, kp, bf);
    // 65536 px / 32 px-per-block = 2048 blocks; 4 waves split N into 4 x 256
    splat_main<<<2048, 256, 0, stream>>>(kp, bf, out);
}

// Round 9
// 30.815 us; speedup vs baseline: 1.1926x; 1.1926x over previous
//
#include <hip/hip_runtime.h>
#include <math.h>

#define NN    1000
#define NPAD  1024
#define NTILE 32              /* 32 n-tiles of 32 gaussians                */
#define TPW   8               /* tiles per wave (4 waves split N 4 x 256)  */
#define LOG2E 1.4426950408889634f
#define LN2PI 1.8378770664093453f

typedef float        f32x4  __attribute__((ext_vector_type(4)));
typedef _Float16     f16x8  __attribute__((ext_vector_type(8)));
typedef unsigned int u32x4v __attribute__((ext_vector_type(4)));

static __device__ __forceinline__ float bperm(int byteaddr, float v) {
    return __builtin_bit_cast(float,
        __builtin_amdgcn_ds_bpermute(byteaddr, __builtin_bit_cast(int, v)));
}
static __device__ __forceinline__ float sigmoidf_(float v) {
    return 1.0f / (1.0f + expf(-v));
}
// e = exp2(Kp - u^2 - M), u = p*x + t   (2 FMA + sub + exp)
static __device__ __forceinline__ float ev(float p, float t, float k, float x, float M) {
    float u = fmaf(p, x, t);
    return __builtin_amdgcn_exp2f(fmaf(-u, u, k) - M);
}
static __device__ __forceinline__ unsigned pk2(float a, float b) {
    return __builtin_bit_cast(unsigned, __builtin_amdgcn_cvt_pkrtz(a, b));
}

// ============ fused kernel: 64 px/block (one image row segment) ============
// phase 0: all params -> LDS (row-folded); pass B: true global max per px;
// pass C: e = exp2(k - M), f16 MFMA accumulate (alpha,r,g,b); epilogue div.
__global__ __launch_bounds__(256, 4) void splat_fused(
    const float* __restrict__ rho, const float* __restrict__ sigma,
    const float* __restrict__ coords, const float* __restrict__ alpha,
    const float* __restrict__ colors, float* __restrict__ out)
{
    __shared__ f32x4  Lp4[NPAD/4], Lt4[NPAD/4], Lk4[NPAD/4];  // 12 KB
    __shared__ u32x4v Lbf[NTILE][4][4];                       //  8 KB [T][col][g]
    __shared__ float  pm[4][64];                              //  1 KB
    __shared__ float  pc[4][64][4];                           //  4 KB

    const int tid  = threadIdx.x;
    const int wave = tid >> 6, lane = tid & 63;
    const int col  = lane & 15, g = lane >> 4;
    const int pxbase = blockIdx.x * 64;
    const float step = 2.0f / 255.0f;
    const float y  = -1.0f + (float)(pxbase >> 8) * step;       // block-uniform
    const float xb = -1.0f + (float)((pxbase & 255) + col) * step;
    const float x0 = xb, x1 = xb + 16.f*step, x2 = xb + 32.f*step, x3 = xb + 48.f*step;

    // ---- phase 0a: derived params (Cholesky log2-domain) + row fold ----
    float* Lp = (float*)Lp4; float* Lt = (float*)Lt4; float* Lk = (float*)Lk4;
    #pragma unroll
    for (int i = 0; i < 4; ++i) {
        int n = tid + 256*i;
        float p, q, r_, u0, v0, K;
        if (n >= NN) { p=q=r_=u0=v0=0.f; K=-1e30f; }   // dummy: contributes 0
        else {
            float sx = tanhf(sigma[2*n]   * 0.5f) + 1e-4f;
            float sy = tanhf(sigma[2*n+1] * 0.5f) + 1e-4f;
            float ra = sigmoidf_(rho[n]) + 1e-6f;
            float cxx = sx*sx + 1e-6f, cyy = sy*sy + 1e-6f;
            float cxy = sx*sy*ra;
            float det = cxx*cyy - cxy*cxy;
            float invdet = 1.0f / det;
            float hl = 0.5f * LOG2E;
            p  = sqrtf(hl * cyy * invdet);
            q  = (-hl * cxy * invdet) / p;
            r_ = sqrtf(hl / cyy);            // exact: b - q^2 = hl/cyy
            float cx = tanhf(coords[2*n])   - 0.5f;
            float cy = tanhf(coords[2*n+1]) - 0.5f;
            u0 = p*cx + q*cy;
            v0 = r_*cy;
            K  = (0.5f * logf(det + 1e-6f) - LN2PI) * LOG2E;
        }
        float t = fmaf(q, y, u0);
        float v = fmaf(r_, y, v0);
        Lp[n] = p; Lt[n] = t; Lk[n] = fmaf(-v, v, K);
    }
    // ---- phase 0b: B-fragments (sigmoid(alpha|rgb) -> f16 pairs) ----
    #pragma unroll
    for (int i = 0; i < 2; ++i) {
        int sid = tid + 256*i;               // 512 slots: T(32) x c(4) x g2(4)
        int T = sid >> 4, c = (sid >> 2) & 3, g2 = sid & 3;
        unsigned w[4] = {0u,0u,0u,0u};
        #pragma unroll
        for (int j = 0; j < 8; ++j) {
            int n = T*32 + g2*8 + j;
            float act = 0.f;
            if (n < NN)
                act = sigmoidf_((c == 0) ? alpha[n] : colors[3*n + c - 1]);
            unsigned short us = __builtin_bit_cast(unsigned short, (_Float16)act);
            w[j>>1] |= (unsigned)us << (16*(j&1));
        }
        Lbf[T][c][g2] = (u32x4v){w[0], w[1], w[2], w[3]};
    }
    __syncthreads();

    // ---- pass B: per-pixel true max (straight-line, no branches) ----
    const int nbase = wave*256 + g*8;
    float mx0=-3.0e38f, mx1=-3.0e38f, mx2=-3.0e38f, mx3=-3.0e38f;
    for (int t = 0; t < TPW; ++t) {
        int q4 = (nbase + t*32) >> 2;
        f32x4 pa = Lp4[q4], pb = Lp4[q4+1];
        f32x4 ta = Lt4[q4], tb = Lt4[q4+1];
        f32x4 ka = Lk4[q4], kb = Lk4[q4+1];
        #pragma unroll
        for (int j = 0; j < 4; ++j) {
            float u;
            u = fmaf(pa[j],x0,ta[j]); mx0 = fmaxf(mx0, fmaf(-u,u,ka[j]));
            u = fmaf(pa[j],x1,ta[j]); mx1 = fmaxf(mx1, fmaf(-u,u,ka[j]));
            u = fmaf(pa[j],x2,ta[j]); mx2 = fmaxf(mx2, fmaf(-u,u,ka[j]));
            u = fmaf(pa[j],x3,ta[j]); mx3 = fmaxf(mx3, fmaf(-u,u,ka[j]));
            u = fmaf(pb[j],x0,tb[j]); mx0 = fmaxf(mx0, fmaf(-u,u,kb[j]));
            u = fmaf(pb[j],x1,tb[j]); mx1 = fmaxf(mx1, fmaf(-u,u,kb[j]));
            u = fmaf(pb[j],x2,tb[j]); mx2 = fmaxf(mx2, fmaf(-u,u,kb[j]));
            u = fmaf(pb[j],x3,tb[j]); mx3 = fmaxf(mx3, fmaf(-u,u,kb[j]));
        }
    }
    const int a16 = ((lane ^ 16) & 63) << 2;     // butterfly across g-groups
    const int a32 = ((lane ^ 32) & 63) << 2;
    mx0 = fmaxf(mx0, bperm(a16, mx0)); mx0 = fmaxf(mx0, bperm(a32, mx0));
    mx1 = fmaxf(mx1, bperm(a16, mx1)); mx1 = fmaxf(mx1, bperm(a32, mx1));
    mx2 = fmaxf(mx2, bperm(a16, mx2)); mx2 = fmaxf(mx2, bperm(a32, mx2));
    mx3 = fmaxf(mx3, bperm(a16, mx3)); mx3 = fmaxf(mx3, bperm(a32, mx3));
    pm[wave][lane] = (g==0) ? mx0 : (g==1) ? mx1 : (g==2) ? mx2 : mx3;
    __syncthreads();
    float M0 = fmaxf(fmaxf(pm[0][col],    pm[1][col]),    fmaxf(pm[2][col],    pm[3][col]));
    float M1 = fmaxf(fmaxf(pm[0][col+16], pm[1][col+16]), fmaxf(pm[2][col+16], pm[3][col+16]));
    float M2 = fmaxf(fmaxf(pm[0][col+32], pm[1][col+32]), fmaxf(pm[2][col+32], pm[3][col+32]));
    float M3 = fmaxf(fmaxf(pm[0][col+48], pm[1][col+48]), fmaxf(pm[2][col+48], pm[3][col+48]));

    // preload this wave's B-fragments (keeps pass-C loop branch-free)
    u32x4v BfR[TPW];
    #pragma unroll
    for (int t = 0; t < TPW; ++t)
        BfR[t] = (col < 4) ? Lbf[wave*TPW + t][col][g] : (u32x4v){0u,0u,0u,0u};

    // ---- pass C: e = exp2(k - M) (bitwise-consistent k), MFMA accumulate ----
    f32x4 C0 = {0.f,0.f,0.f,0.f}, C1 = {0.f,0.f,0.f,0.f};
    f32x4 C2 = {0.f,0.f,0.f,0.f}, C3 = {0.f,0.f,0.f,0.f};
    for (int t = 0; t < TPW; ++t) {
        int q4 = (nbase + t*32) >> 2;
        f32x4 pa = Lp4[q4], pb = Lp4[q4+1];
        f32x4 ta = Lt4[q4], tb = Lt4[q4+1];
        f32x4 ka = Lk4[q4], kb = Lk4[q4+1];
        f16x8 Bf = __builtin_bit_cast(f16x8, BfR[t]);

        u32x4v W;
        W = (u32x4v){ pk2(ev(pa[0],ta[0],ka[0],x0,M0), ev(pa[1],ta[1],ka[1],x0,M0)),
                      pk2(ev(pa[2],ta[2],ka[2],x0,M0), ev(pa[3],ta[3],ka[3],x0,M0)),
                      pk2(ev(pb[0],tb[0],kb[0],x0,M0), ev(pb[1],tb[1],kb[1],x0,M0)),
                      pk2(ev(pb[2],tb[2],kb[2],x0,M0), ev(pb[3],tb[3],kb[3],x0,M0)) };
        C0 = __builtin_amdgcn_mfma_f32_16x16x32_f16(__builtin_bit_cast(f16x8, W), Bf, C0, 0, 0, 0);
        W = (u32x4v){ pk2(ev(pa[0],ta[0],ka[0],x1,M1), ev(pa[1],ta[1],ka[1],x1,M1)),
                      pk2(ev(pa[2],ta[2],ka[2],x1,M1), ev(pa[3],ta[3],ka[3],x1,M1)),
                      pk2(ev(pb[0],tb[0],kb[0],x1,M1), ev(pb[1],tb[1],kb[1],x1,M1)),
                      pk2(ev(pb[2],tb[2],kb[2],x1,M1), ev(pb[3],tb[3],kb[3],x1,M1)) };
        C1 = __builtin_amdgcn_mfma_f32_16x16x32_f16(__builtin_bit_cast(f16x8, W), Bf, C1, 0, 0, 0);
        W = (u32x4v){ pk2(ev(pa[0],ta[0],ka[0],x2,M2), ev(pa[1],ta[1],ka[1],x2,M2)),
                      pk2(ev(pa[2],ta[2],ka[2],x2,M2), ev(pa[3],ta[3],ka[3],x2,M2)),
                      pk2(ev(pb[0],tb[0],kb[0],x2,M2), ev(pb[1],tb[1],kb[1],x2,M2)),
                      pk2(ev(pb[2],tb[2],kb[2],x2,M2), ev(pb[3],tb[3],kb[3],x2,M2)) };
        C2 = __builtin_amdgcn_mfma_f32_16x16x32_f16(__builtin_bit_cast(f16x8, W), Bf, C2, 0, 0, 0);
        W = (u32x4v){ pk2(ev(pa[0],ta[0],ka[0],x3,M3), ev(pa[1],ta[1],ka[1],x3,M3)),
                      pk2(ev(pa[2],ta[2],ka[2],x3,M3), ev(pa[3],ta[3],ka[3],x3,M3)),
                      pk2(ev(pb[0],tb[0],kb[0],x3,M3), ev(pb[1],tb[1],kb[1],x3,M3)),
                      pk2(ev(pb[2],tb[2],kb[2],x3,M3), ev(pb[3],tb[3],kb[3],x3,M3)) };
        C3 = __builtin_amdgcn_mfma_f32_16x16x32_f16(__builtin_bit_cast(f16x8, W), Bf, C3, 0, 0, 0);
    }

    // ---- epilogue: cross-wave sum (shared global M -> plain addition) ----
    if (col < 4) {
        #pragma unroll
        for (int i = 0; i < 4; ++i) {        // C layout: col=ch, row=4g+i
            int row = 4*g + i;
            pc[wave][row     ][col] = C0[i];
            pc[wave][row + 16][col] = C1[i];
            pc[wave][row + 32][col] = C2[i];
            pc[wave][row + 48][col] = C3[i];
        }
    }
    __syncthreads();
    if (tid < 64) {
        int px = tid;
        float A = pc[0][px][0] + pc[1][px][0] + pc[2][px][0] + pc[3][px][0];
        float R = pc[0][px][1] + pc[1][px][1] + pc[2][px][1] + pc[3][px][1];
        float G = pc[0][px][2] + pc[1][px][2] + pc[2][px][2] + pc[3][px][2];
        float B = pc[0][px][3] + pc[1][px][3] + pc[2][px][3] + pc[3][px][3];
        float inv = 1.0f / (A + 1e-6f);
        int q = (pxbase + px) * 3;
        out[q] = R*inv; out[q+1] = G*inv; out[q+2] = B*inv;
    }
}

extern "C" void kernel_launch(void* const* d_in, const int* in_sizes, int n_in,
                              void* d_out, int out_size, void* d_ws, size_t ws_size,
                              hipStream_t stream) {
    const float* rho    = (const float*)d_in[0];
    const float* sigma  = (const float*)d_in[1];
    const float* coords = (const float*)d_in[2];
    const float* alpha  = (const float*)d_in[3];
    const float* colors = (const float*)d_in[4];
    float* out = (float*)d_out;   // xy derived analytically (validated r8)

    // 65536 px / 64 px-per-block = 1024 blocks = exactly 4 blocks/CU
    splat_fused<<<1024, 256, 0, stream>>>(rho, sigma, coords, alpha, colors, out);
}